// Round 10
// baseline (214.885 us; speedup 1.0000x reference)
//
#include <hip/hip_runtime.h>
#include <math.h>

#define NN      512     // N (columns of x)
#define KK      513     // K
#define BB      65536   // batch
#define TROWS   512     // table rows, t = 0..511
#define TCOLS   513     // table cols, g = 0..512
#define T16STR  528     // u32 stride per table row (2112 B, 64B-aligned)

#define RPB     64            // rows per block
#define NSEG    8             // segments per row
#define SEGW    64            // columns per segment
#define BLK     (RPB * NSEG)  // 512 threads = 8 waves
#define XSTR    129           // LDS row stride in u32 (128 + 1 pad: conflict-free both phases)

typedef int iv4 __attribute__((ext_vector_type(4)));

__device__ __forceinline__ unsigned f2bf(float f) {   // RNE f32 -> bf16 (finite only)
    unsigned u = __float_as_uint(f);
    return (u + 0x7fffu + ((u >> 16) & 1u)) >> 16;
}

// T16[t*T16STR + g] = pack(bf16 logsm(c=0), bf16 logsm(c=1)); edges/unreachable = 0 (log 1)
__global__ void build_table_kernel(const float* __restrict__ W, unsigned* __restrict__ T16) {
    int idx = blockIdx.x * blockDim.x + threadIdx.x;
    if (idx >= TROWS * TCOLS) return;
    int t = idx / TCOLS;
    int g = idx - t * TCOLS;
    float v0 = 0.f, v1 = 0.f;
    if (t >= 1 && g >= 1 && g <= t) {
        const float* w = W + ((size_t)(t - 1) * (KK - 1) + (g - 1)) * 2;
        float w0 = w[0], w1 = w[1];
        float m  = fmaxf(w0, w1);
        float lse = m + logf(expf(w0 - m) + expf(w1 - m));
        v0 = w0 - lse;
        v1 = w1 - lse;
    }
    T16[t * T16STR + g] = f2bf(v0) | (f2bf(v1) << 16);
}

// logE[k] = endW[k] - logsumexp(endW)   (513 entries, f32), one wave
__global__ void build_endw_kernel(const float* __restrict__ endW, float* __restrict__ logE) {
    int lane = threadIdx.x;  // 0..63
    float vals[9];
    float m = -1e30f;
    #pragma unroll
    for (int k = 0; k < 9; ++k) {
        int i = lane + 64 * k;
        vals[k] = (i < KK) ? endW[i] : -1e30f;
        m = fmaxf(m, vals[k]);
    }
    #pragma unroll
    for (int d = 32; d >= 1; d >>= 1) m = fmaxf(m, __shfl_xor(m, d, 64));
    float s = 0.f;
    #pragma unroll
    for (int k = 0; k < 9; ++k) s += expf(vals[k] - m);
    #pragma unroll
    for (int d = 32; d >= 1; d >>= 1) s += __shfl_xor(s, d, 64);
    float lse = m + logf(s);
    #pragma unroll
    for (int k = 0; k < 9; ++k) {
        int i = lane + 64 * k;
        if (i < KK) logE[i] = endW[i] - lse;
    }
}

// R6 structure (4 blocks/CU, cross-block TLP) + bf16-packed table.
// A/B vs R9: x loads are now PLAIN (cached) loads — nt flag removed.
// Block = 512 threads = 64 rows x 8 segments (wave i = segment i).
__global__ __launch_bounds__(BLK, 8) void pc_main_kernel(
    const int* __restrict__ x, const unsigned* __restrict__ T16,
    const float* __restrict__ logE, float* __restrict__ out)
{
    __shared__ unsigned xb[RPB * XSTR];        // packed 0/1 bytes, 4 cols per u32
    __shared__ int      segsum[NSEG * RPB];
    __shared__ float    partial[NSEG * RPB];

    const int tid  = threadIdx.x;
    const int row0 = blockIdx.x * RPB;

    // ---- phase 1: coalesced load + byte-pack into LDS ----
    {
        const iv4* tile = (const iv4*)(x + (size_t)row0 * NN);  // 8192 int4, linear
        #pragma unroll
        for (int j = 0; j < 16; ++j) {
            int i = tid + BLK * j;            // lane-consecutive -> minimal TA lines
            iv4 a = tile[i];                  // plain cached load (A/B: no nt)
            unsigned m = (unsigned)(a.x & 1) | ((unsigned)(a.y & 1) << 8)
                       | ((unsigned)(a.z & 1) << 16) | ((unsigned)(a.w & 1) << 24);
            xb[(i >> 7) * XSTR + (i & 127)] = m;
        }
    }
    __syncthreads();

    // ---- phase 2: own-segment words + segment sums ----
    const int seg  = tid >> 6;    // wave index = segment
    const int lane = tid & 63;    // row within block

    unsigned w[16];
    int ssum = 0;
    #pragma unroll
    for (int m = 0; m < 16; ++m) {
        w[m] = xb[lane * XSTR + seg * 16 + m];   // stride 129 -> conflict-free
        ssum += __popc(w[m]);                    // bytes are 0x00/0x01
    }
    segsum[seg * 64 + lane] = ssum;
    __syncthreads();

    int g = 0, gtot = 0;
    #pragma unroll
    for (int s = 0; s < NSEG; ++s) {
        int v = segsum[s * 64 + lane];
        if (s < seg) g += v;
        gtot += v;
    }

    // ---- phase 3: bf16-table gathers (one table row per wave-instr) ----
    float a0 = 0.f, a1 = 0.f, a2 = 0.f, a3 = 0.f;
    const unsigned* Tseg = T16 + (size_t)(seg * SEGW) * T16STR;
    #pragma unroll
    for (int m = 0; m < 16; ++m) {
        const unsigned* Tm = Tseg + (size_t)(4 * m) * T16STR;
        unsigned wm = w[m];
        int b0 = wm & 1;         g += b0; unsigned u0 = Tm[0 * T16STR + g];
        a0 += __uint_as_float(b0 ? (u0 & 0xffff0000u) : (u0 << 16));
        int b1 = (wm >> 8)  & 1; g += b1; unsigned u1 = Tm[1 * T16STR + g];
        a1 += __uint_as_float(b1 ? (u1 & 0xffff0000u) : (u1 << 16));
        int b2 = (wm >> 16) & 1; g += b2; unsigned u2 = Tm[2 * T16STR + g];
        a2 += __uint_as_float(b2 ? (u2 & 0xffff0000u) : (u2 << 16));
        int b3 = (wm >> 24) & 1; g += b3; unsigned u3 = Tm[3 * T16STR + g];
        a3 += __uint_as_float(b3 ? (u3 & 0xffff0000u) : (u3 << 16));
    }
    partial[seg * 64 + lane] = (a0 + a1) + (a2 + a3);
    __syncthreads();

    // ---- phase 4: per-row reduction (wave 0 only) ----
    if (seg == 0) {
        float s = logE[gtot];
        #pragma unroll
        for (int t = 0; t < NSEG; ++t) s += partial[t * 64 + lane];
        out[row0 + lane] = s;
    }
}

extern "C" void kernel_launch(void* const* d_in, const int* in_sizes, int n_in,
                              void* d_out, int out_size, void* d_ws, size_t ws_size,
                              hipStream_t stream)
{
    const int*   x    = (const int*)d_in[0];
    const float* W    = (const float*)d_in[1];
    const float* endW = (const float*)d_in[2];
    float*       out  = (float*)d_out;

    unsigned* T16  = (unsigned*)d_ws;                               // 512*528*4 = 1,081,344 B
    float*    logE = (float*)((char*)d_ws + (size_t)TROWS * T16STR * sizeof(unsigned));

    {
        int total  = TROWS * TCOLS;
        int blocks = (total + 255) / 256;
        build_table_kernel<<<blocks, 256, 0, stream>>>(W, T16);
    }
    build_endw_kernel<<<1, 64, 0, stream>>>(endW, logE);
    pc_main_kernel<<<BB / RPB, BLK, 0, stream>>>(x, T16, logE, out);
}

// Round 11
// 211.288 us; speedup vs baseline: 1.0170x; 1.0170x over previous
//
#include <hip/hip_runtime.h>
#include <math.h>

#define NN      512     // N (columns of x)
#define KK      513     // K
#define BB      65536   // batch
#define TROWS   512     // table rows, t = 0..511
#define TCOLS   513     // table cols, g = 0..512
#define T16STR  528     // u32 stride per table row (2112 B, 64B-aligned)

#define BLK     256           // 4 waves per block; each wave owns 8 rows (wave-autonomous)

typedef int iv4 __attribute__((ext_vector_type(4)));

__device__ __forceinline__ unsigned f2bf(float f) {   // RNE f32 -> bf16 (finite only)
    unsigned u = __float_as_uint(f);
    return (u + 0x7fffu + ((u >> 16) & 1u)) >> 16;
}

// T16[t*T16STR + g] = pack(bf16 logsm(c=0), bf16 logsm(c=1)); edges/unreachable = 0.
// Block 0, wave 0 additionally builds logE[k] = endW[k] - lse(endW) (513 f32).
__global__ void build_table_kernel(const float* __restrict__ W, const float* __restrict__ endW,
                                   unsigned* __restrict__ T16, float* __restrict__ logE) {
    int idx = blockIdx.x * blockDim.x + threadIdx.x;
    if (idx < TROWS * TCOLS) {
        int t = idx / TCOLS;
        int g = idx - t * TCOLS;
        float v0 = 0.f, v1 = 0.f;
        if (t >= 1 && g >= 1 && g <= t) {
            const float* w = W + ((size_t)(t - 1) * (KK - 1) + (g - 1)) * 2;
            float w0 = w[0], w1 = w[1];
            float m  = fmaxf(w0, w1);
            float lse = m + __logf(__expf(w0 - m) + __expf(w1 - m));
            v0 = w0 - lse;
            v1 = w1 - lse;
        }
        T16[t * T16STR + g] = f2bf(v0) | (f2bf(v1) << 16);
    }
    if (blockIdx.x == 0 && threadIdx.x < 64) {
        int lane = threadIdx.x;
        float vals[9];
        float m = -1e30f;
        #pragma unroll
        for (int k = 0; k < 9; ++k) {
            int i = lane + 64 * k;
            vals[k] = (i < KK) ? endW[i] : -1e30f;
            m = fmaxf(m, vals[k]);
        }
        #pragma unroll
        for (int d = 32; d >= 1; d >>= 1) m = fmaxf(m, __shfl_xor(m, d, 64));
        float s = 0.f;
        #pragma unroll
        for (int k = 0; k < 9; ++k) s += __expf(vals[k] - m);
        #pragma unroll
        for (int d = 32; d >= 1; d >>= 1) s += __shfl_xor(s, d, 64);
        float lse = m + __logf(s);
        #pragma unroll
        for (int k = 0; k < 9; ++k) {
            int i = lane + 64 * k;
            if (i < KK) logE[i] = endW[i] - lse;
        }
    }
}

// Wave-autonomous: each wave owns 8 rows (16 KB), no __syncthreads anywhere.
//  load:   16 lane-consecutive int4 instrs (1 KB each), nibble-pack to p0/p1.
//  xpose:  wave-local LDS exchange (512 B/wave), sched_barrier fence only.
//  prefix: 3x shfl_up over the 8 col-segments of each row.
//  gather: 64 bf16-table lookups/thread (table rows 64s+k, clustered g, L2-hot).
//  reduce: 3x shfl_xor across segments; lane s==7 writes out + logE[row total].
// Waves drift out of phase -> gather/popcount overlap other waves' HBM stream.
__global__ __launch_bounds__(BLK, 8) void pc_main_kernel(
    const int* __restrict__ x, const unsigned* __restrict__ T16,
    const float* __restrict__ logE, float* __restrict__ out)
{
    __shared__ unsigned xposed[4 * 128];   // per wave: [0..63]=p0, [64..127]=p1

    const int tid  = threadIdx.x;
    const int wid  = tid >> 6;
    const int lane = tid & 63;
    const int gw   = blockIdx.x * 4 + wid;     // global wave id; rows [8gw, 8gw+8)
    const int ridx = lane & 7;                 // row handled in gather phase
    const int s    = lane >> 3;                // 64-col segment handled in gather phase

    // ---- load + nibble-pack (wave-private tile: 1024 int4) ----
    const iv4* xt = (const iv4*)(x + (size_t)gw * (8 * NN));
    unsigned p0 = 0, p1 = 0;
    {
        iv4 A[8];
        #pragma unroll
        for (int j = 0; j < 8; ++j) A[j] = __builtin_nontemporal_load(&xt[j * 64 + lane]);
        #pragma unroll
        for (int j = 0; j < 8; ++j) {
            unsigned nib = (unsigned)(A[j].x & 1) | ((unsigned)(A[j].y & 1) << 1)
                         | ((unsigned)(A[j].z & 1) << 2) | ((unsigned)(A[j].w & 1) << 3);
            p0 |= nib << (4 * j);
        }
        #pragma unroll
        for (int j = 0; j < 8; ++j) A[j] = __builtin_nontemporal_load(&xt[(8 + j) * 64 + lane]);
        #pragma unroll
        for (int j = 0; j < 8; ++j) {
            unsigned nib = (unsigned)(A[j].x & 1) | ((unsigned)(A[j].y & 1) << 1)
                         | ((unsigned)(A[j].z & 1) << 2) | ((unsigned)(A[j].w & 1) << 3);
            p1 |= nib << (4 * j);
        }
    }

    // ---- wave-local transpose through LDS (no block barrier) ----
    unsigned* wb = &xposed[wid * 128];
    wb[lane]      = p0;     // p0(l): rows 0-3, lane l covers cols {256h+4l+b}, j=2r+h
    wb[64 + lane] = p1;     // p1(l): rows 4-7
    __builtin_amdgcn_sched_barrier(0);   // keep ds_reads after ds_writes

    const unsigned base  = ((ridx < 4) ? 0u : 64u) + 16u * (s & 3);  // half h = s>>2
    const int      shift = 4 * ((2 * ridx + (s >> 2)) & 7);
    unsigned lo = 0, hi = 0;
    #pragma unroll
    for (int m = 0; m < 8; ++m)  lo |= ((wb[base + m] >> shift) & 0xFu) << (4 * m);
    #pragma unroll
    for (int m = 8; m < 16; ++m) hi |= ((wb[base + m] >> shift) & 0xFu) << (4 * (m - 8));

    // ---- per-segment popcount + inclusive prefix over s (per row ridx) ----
    int pc  = __popc(lo) + __popc(hi);
    int inc = pc, t1;
    t1 = __shfl_up(inc, 8,  64); if (s >= 1) inc += t1;
    t1 = __shfl_up(inc, 16, 64); if (s >= 2) inc += t1;
    t1 = __shfl_up(inc, 32, 64); if (s >= 4) inc += t1;
    int g = inc - pc;            // exclusive start g for this segment

    // ---- gathers: 64 cols, table row c = 64s+k, bf16 select by bit ----
    float a0 = 0.f, a1 = 0.f, a2 = 0.f, a3 = 0.f;
    const unsigned* Ts = T16 + (size_t)(64 * s) * T16STR;
    #pragma unroll
    for (int k = 0; k < 32; ++k) {
        int b = (lo >> k) & 1; g += b;
        unsigned u = Ts[k * T16STR + g];
        float v = __uint_as_float(b ? (u & 0xffff0000u) : (u << 16));
        if      ((k & 3) == 0) a0 += v;
        else if ((k & 3) == 1) a1 += v;
        else if ((k & 3) == 2) a2 += v;
        else                   a3 += v;
    }
    #pragma unroll
    for (int k = 0; k < 32; ++k) {
        int b = (hi >> k) & 1; g += b;
        unsigned u = Ts[(32 + k) * T16STR + g];
        float v = __uint_as_float(b ? (u & 0xffff0000u) : (u << 16));
        if      ((k & 3) == 0) a0 += v;
        else if ((k & 3) == 1) a1 += v;
        else if ((k & 3) == 2) a2 += v;
        else                   a3 += v;
    }

    // ---- reduce across the 8 segments of each row ----
    float part = (a0 + a1) + (a2 + a3);
    part += __shfl_xor(part, 8,  64);
    part += __shfl_xor(part, 16, 64);
    part += __shfl_xor(part, 32, 64);
    if (s == 7)                              // this lane's inc == row total g
        out[gw * 8 + ridx] = part + logE[inc];
}

extern "C" void kernel_launch(void* const* d_in, const int* in_sizes, int n_in,
                              void* d_out, int out_size, void* d_ws, size_t ws_size,
                              hipStream_t stream)
{
    const int*   x    = (const int*)d_in[0];
    const float* W    = (const float*)d_in[1];
    const float* endW = (const float*)d_in[2];
    float*       out  = (float*)d_out;

    unsigned* T16  = (unsigned*)d_ws;                               // 512*528*4 = 1,081,344 B
    float*    logE = (float*)((char*)d_ws + (size_t)TROWS * T16STR * sizeof(unsigned));

    {
        int total  = TROWS * TCOLS;                 // 262656 = 1026 * 256 exactly
        int blocks = (total + BLK - 1) / BLK;
        build_table_kernel<<<blocks, BLK, 0, stream>>>(W, endW, T16, logE);
    }
    pc_main_kernel<<<BB / (8 * 4), BLK, 0, stream>>>(x, T16, logE, out);
}

// Round 13
// 193.919 us; speedup vs baseline: 1.1081x; 1.0896x over previous
//
#include <hip/hip_runtime.h>
#include <math.h>

#define NN      512     // N (columns of x)
#define KK      513     // K
#define BB      65536   // batch
#define TROWS   512     // table rows, t = 0..511
#define TCOLS   513     // table cols, g = 0..512
#define T16STR  528     // u32 stride per table row (2112 B, 64B-aligned)

#define TILE_R  32            // rows per tile
#define TPB     2             // tiles per block (software pipeline)
#define BLK     256           // 4 waves; thread = (row r=tid&31, seg s=tid>>5)
#define XSTR    129           // LDS words per row (128 chunks + 1 pad)
#define TILE_I4 (TILE_R * NN / 4)   // int4 per tile = 4096

typedef int iv4 __attribute__((ext_vector_type(4)));

__device__ __forceinline__ unsigned f2bf(float f) {   // RNE f32 -> bf16 (finite only)
    unsigned u = __float_as_uint(f);
    return (u + 0x7fffu + ((u >> 16) & 1u)) >> 16;
}

// T16[t*T16STR + g] = pack(bf16 logsm(c=0), bf16 logsm(c=1)); edges/unreachable = 0.
// Block 0 wave 0 additionally builds logE[k] = endW[k] - lse(endW).
__global__ void build_table_kernel(const float* __restrict__ W, const float* __restrict__ endW,
                                   unsigned* __restrict__ T16, float* __restrict__ logE) {
    int idx = blockIdx.x * blockDim.x + threadIdx.x;
    if (idx < TROWS * TCOLS) {
        int t = idx / TCOLS;
        int g = idx - t * TCOLS;
        float v0 = 0.f, v1 = 0.f;
        if (t >= 1 && g >= 1 && g <= t) {
            const float* w = W + ((size_t)(t - 1) * (KK - 1) + (g - 1)) * 2;
            float w0 = w[0], w1 = w[1];
            float m  = fmaxf(w0, w1);
            float lse = m + __logf(__expf(w0 - m) + __expf(w1 - m));
            v0 = w0 - lse;
            v1 = w1 - lse;
        }
        T16[t * T16STR + g] = f2bf(v0) | (f2bf(v1) << 16);
    }
    if (blockIdx.x == 0 && threadIdx.x < 64) {
        int lane = threadIdx.x;
        float vals[9];
        float m = -1e30f;
        #pragma unroll
        for (int k = 0; k < 9; ++k) {
            int i = lane + 64 * k;
            vals[k] = (i < KK) ? endW[i] : -1e30f;
            m = fmaxf(m, vals[k]);
        }
        #pragma unroll
        for (int d = 32; d >= 1; d >>= 1) m = fmaxf(m, __shfl_xor(m, d, 64));
        float s = 0.f;
        #pragma unroll
        for (int k = 0; k < 9; ++k) s += __expf(vals[k] - m);
        #pragma unroll
        for (int d = 32; d >= 1; d >>= 1) s += __shfl_xor(s, d, 64);
        float lse = m + __logf(s);
        #pragma unroll
        for (int k = 0; k < 9; ++k) {
            int i = lane + 64 * k;
            if (i < KK) logE[i] = endW[i] - lse;
        }
    }
}

// 256 threads = 32 rows x 8 segs(64 cols); 2-tile software pipeline.
// Per tile: read own-seg words (LDS, conflict-free), popc+prefix -> g, issue
// ALL 64 gathers, consume 48, issue next tile's 16 staged loads (younger than
// every gather -> no consume drains them), consume last 16, pack+ds_write
// staged, barrier, reduce. Staged loads stream on HBM during the gather
// phase -> load/gather phases overlap device-wide.
__global__ __launch_bounds__(BLK, 4) void pc_main_kernel(
    const int* __restrict__ x, const unsigned* __restrict__ T16,
    const float* __restrict__ logE, float* __restrict__ out)
{
    __shared__ unsigned xb[2][TILE_R * XSTR];   // byte-packed: word = 4 cols of one row
    __shared__ int      segsum[8 * TILE_R];
    __shared__ float    partial[8 * TILE_R];

    const int tid  = threadIdx.x;
    const int r    = tid & 31;          // row within tile
    const int s    = tid >> 5;          // 64-col segment (0..7)
    const int row0 = blockIdx.x * (TILE_R * TPB);

    const iv4* tb = (const iv4*)(x + (size_t)row0 * NN);   // TILE_I4=4096 int4 per tile

    // ---- prologue: load tile 0, pack, stage to LDS buf 0 ----
    iv4 A[16];
    #pragma unroll
    for (int j = 0; j < 16; ++j) A[j] = __builtin_nontemporal_load(&tb[tid + BLK * j]);
    #pragma unroll
    for (int j = 0; j < 16; ++j) {
        int i = tid + BLK * j;
        unsigned m = (unsigned)(A[j].x & 1) | ((unsigned)(A[j].y & 1) << 8)
                   | ((unsigned)(A[j].z & 1) << 16) | ((unsigned)(A[j].w & 1) << 24);
        xb[0][(i >> 7) * XSTR + (i & 127)] = m;
    }
    __syncthreads();

    #pragma unroll
    for (int t = 0; t < TPB; ++t) {
        // ---- own-segment words + popcount ----
        unsigned w[16];
        int ssum = 0;
        #pragma unroll
        for (int m = 0; m < 16; ++m) {
            w[m] = xb[t][r * XSTR + s * 16 + m];    // (r*129+16s+m)%32 spans banks: free
            ssum += __popc(w[m]);                   // bytes are 0x00/0x01
        }
        segsum[s * TILE_R + r] = ssum;
        __syncthreads();

        int g = 0, gtot = 0;
        #pragma unroll
        for (int q = 0; q < 8; ++q) {
            int v = segsum[q * TILE_R + r];
            if (q < s) g += v;
            gtot += v;
        }

        // ---- issue ALL 64 gathers (one table row pair per wave-instr) ----
        unsigned u[64];
        const unsigned* Ts = T16 + (size_t)(s * 64) * T16STR;
        #pragma unroll
        for (int m = 0; m < 16; ++m) {
            #pragma unroll
            for (int q = 0; q < 4; ++q) {
                int b = (w[m] >> (8 * q)) & 1;
                g += b;
                u[4 * m + q] = Ts[(4 * m + q) * T16STR + g];
            }
        }

        // ---- consume gathers 0..47 ----
        float a0 = 0.f, a1 = 0.f, a2 = 0.f, a3 = 0.f;
        #pragma unroll
        for (int k = 0; k < 48; ++k) {
            int b = (w[k >> 2] >> (8 * (k & 3))) & 1;
            float v = __uint_as_float(b ? (u[k] & 0xffff0000u) : (u[k] << 16));
            if      ((k & 3) == 0) a0 += v;
            else if ((k & 3) == 1) a1 += v;
            else if ((k & 3) == 2) a2 += v;
            else                   a3 += v;
        }

        // ---- issue next tile's staged loads (younger than all gathers) ----
        if (t + 1 < TPB) {
            __builtin_amdgcn_sched_barrier(0);
            #pragma unroll
            for (int j = 0; j < 16; ++j)
                A[j] = __builtin_nontemporal_load(&tb[TILE_I4 + tid + BLK * j]);
            __builtin_amdgcn_sched_barrier(0);
        }

        // ---- consume gathers 48..63 (older than staged: no drain) ----
        #pragma unroll
        for (int k = 48; k < 64; ++k) {
            int b = (w[k >> 2] >> (8 * (k & 3))) & 1;
            float v = __uint_as_float(b ? (u[k] & 0xffff0000u) : (u[k] << 16));
            if      ((k & 3) == 0) a0 += v;
            else if ((k & 3) == 1) a1 += v;
            else if ((k & 3) == 2) a2 += v;
            else                   a3 += v;
        }
        partial[s * TILE_R + r] = (a0 + a1) + (a2 + a3);

        // ---- pack + stage next tile into the other LDS buffer ----
        if (t + 1 < TPB) {
            #pragma unroll
            for (int j = 0; j < 16; ++j) {
                int i = tid + BLK * j;
                unsigned m = (unsigned)(A[j].x & 1) | ((unsigned)(A[j].y & 1) << 8)
                           | ((unsigned)(A[j].z & 1) << 16) | ((unsigned)(A[j].w & 1) << 24);
                xb[t + 1][(i >> 7) * XSTR + (i & 127)] = m;
            }
        }
        __syncthreads();   // partial ready AND next buffer staged

        if (s == 0) {
            float o = logE[gtot];
            #pragma unroll
            for (int q = 0; q < 8; ++q) o += partial[q * TILE_R + r];
            out[row0 + t * TILE_R + r] = o;
        }
    }
}

extern "C" void kernel_launch(void* const* d_in, const int* in_sizes, int n_in,
                              void* d_out, int out_size, void* d_ws, size_t ws_size,
                              hipStream_t stream)
{
    const int*   x    = (const int*)d_in[0];
    const float* W    = (const float*)d_in[1];
    const float* endW = (const float*)d_in[2];
    float*       out  = (float*)d_out;

    unsigned* T16  = (unsigned*)d_ws;                               // 512*528*4 = 1,081,344 B
    float*    logE = (float*)((char*)d_ws + (size_t)TROWS * T16STR * sizeof(unsigned));

    {
        int total  = TROWS * TCOLS;
        int blocks = (total + BLK - 1) / BLK;
        build_table_kernel<<<blocks, BLK, 0, stream>>>(W, endW, T16, logE);
    }
    pc_main_kernel<<<BB / (TILE_R * TPB), BLK, 0, stream>>>(x, T16, logE, out);
}